// Round 19
// baseline (160.976 us; speedup 1.0000x reference)
//
#include <hip/hip_runtime.h>
#include <math.h>

typedef _Float16 h8 __attribute__((ext_vector_type(8)));
typedef float    f4v __attribute__((ext_vector_type(4)));

#define N_TRAIN 400000
#define DIMS    27
#define BQ      512
#define NCLS    11
#define KNN     3
#define NB      500            // pass-1 blocks
#define P1T     1024           // pass-1 threads (16 waves)
#define PTS_BLK 800            // points per block (500*800 = 400000 exact)
#define PTS_SUP 160            // points per super-tile
#define NSUP    5
#define NPT     10
#define RAWF    4320           // floats per super-tile (160*27)
#define TILE_B  1024           // conv bytes per ptile (hi fragments only)
#define NC      (NB * KNN)     // candidates per query (1500)
#define SCB     391            // k_scale blocks (391*256 = 100096 >= 100000 groups of 4 rows)
#define P2T     512            // pass-2 threads (8 waves)

#define U64MAX 0xFFFFFFFFFFFFFFFFULL

// ---------------- scale = max(|train|, axis=0) — register-resident, no LDS staging ----------------
// (R6-verified kernel.)
__global__ __launch_bounds__(256) void k_scale(const float* __restrict__ train,
                                               unsigned* __restrict__ scale_u) {
    __shared__ float red[4][DIMS];
    int tid = threadIdx.x;
    int lane = tid & 63, w = tid >> 6;
    int g = blockIdx.x * 256 + tid;            // 4-row group id
    float m[DIMS];
#pragma unroll
    for (int d = 0; d < DIMS; ++d) m[d] = 0.f;
    if (g < N_TRAIN / 4) {
        const uint4* p = (const uint4*)(train + (size_t)g * (4 * DIMS));
#pragma unroll
        for (int k = 0; k < DIMS; ++k) {
            uint4 v = p[k];
            m[(4 * k + 0) % DIMS] = fmaxf(m[(4 * k + 0) % DIMS], fabsf(__uint_as_float(v.x)));
            m[(4 * k + 1) % DIMS] = fmaxf(m[(4 * k + 1) % DIMS], fabsf(__uint_as_float(v.y)));
            m[(4 * k + 2) % DIMS] = fmaxf(m[(4 * k + 2) % DIMS], fabsf(__uint_as_float(v.z)));
            m[(4 * k + 3) % DIMS] = fmaxf(m[(4 * k + 3) % DIMS], fabsf(__uint_as_float(v.w)));
        }
    }
#pragma unroll
    for (int d = 0; d < DIMS; ++d) {           // wave butterfly (27 dims x 6 steps)
        float t = m[d];
#pragma unroll
        for (int st = 1; st < 64; st <<= 1) t = fmaxf(t, __shfl_xor(t, st, 64));
        m[d] = t;
    }
    if (lane == 0) {
#pragma unroll
        for (int d = 0; d < DIMS; ++d) red[w][d] = m[d];
    }
    __syncthreads();
    if (tid < DIMS) {
        float v = fmaxf(fmaxf(red[0][tid], red[1][tid]), fmaxf(red[2][tid], red[3][tid]));
        atomicMax(&scale_u[tid], __float_as_uint(v)); // values >= 0: uint order == float order
    }
}

// ---------------- query prep: f16 B-fragments (hi only) ----------------
__global__ __launch_bounds__(64) void k_qprep(const float* __restrict__ query,
                                              const unsigned* __restrict__ scale_u,
                                              _Float16* __restrict__ Qhi) {
    int q = blockIdx.x * 64 + threadIdx.x;
    if (q >= BQ) return;
    const float* r = query + (size_t)q * DIMS;
#pragma unroll
    for (int d = 0; d < 32; ++d) {
        _Float16 hi = (_Float16)0.f;
        if (d < DIMS) {
            float sc = __uint_as_float(scale_u[d]);
            float inv = (sc != 0.f) ? 1.f / sc : 0.f;   // divide_no_nan
            hi = (_Float16)(r[d] * inv);
        }
        // d>=27: 0 (A slots 27..31 are 0; xn folded via f32 C-init)
        Qhi[q * 32 + d] = hi;
    }
}

// lexicographic (key, idx) insert into ascending sorted triple — matches top_k ties
__device__ __forceinline__ void insert3(float d, int i, float* bd, int* bi) {
    if (d < bd[2] || (d == bd[2] && i < bi[2])) {
        if (d < bd[1] || (d == bd[1] && i < bi[1])) {
            bd[2] = bd[1]; bi[2] = bi[1];
            if (d < bd[0] || (d == bd[0] && i < bi[0])) {
                bd[1] = bd[0]; bi[1] = bi[0];
                bd[0] = d; bi[0] = i;
            } else { bd[1] = d; bi[1] = i; }
        } else { bd[2] = d; bi[2] = i; }
    }
}

// 64-bit xor-shuffle via two 32-bit shuffles
__device__ __forceinline__ unsigned long long shfl_xor_u64(unsigned long long v, int m) {
    unsigned lo = (unsigned)v, hi = (unsigned)(v >> 32);
    lo = __shfl_xor(lo, m, 64);
    hi = __shfl_xor(hi, m, 64);
    return ((unsigned long long)hi << 32) | lo;
}

// branchless insert into ascending sorted-3 of u64 (keep 3 smallest)
__device__ __forceinline__ void ins3u64(unsigned long long e,
                                        unsigned long long& t0,
                                        unsigned long long& t1,
                                        unsigned long long& t2) {
    unsigned long long a  = e < t2 ? e : t2;     // candidate enters bottom slot
    unsigned long long n2 = t1 > a ? t1 : a;
    unsigned long long n1 = t1 < a ? t1 : a;
    t2 = n2;
    unsigned long long m1 = t0 > n1 ? t0 : n1;
    t0 = t0 < n1 ? t0 : n1;
    t1 = m1;
}

__device__ __forceinline__ void stage16(const float* g, float* l) {
    __builtin_amdgcn_global_load_lds((const __attribute__((address_space(1))) void*)g,
                                     (__attribute__((address_space(3))) void*)l, 16, 0, 0);
}

// tracker: exact top-2 insert via med3 (invariant kb0 >= kb1); R14-verified form
#define TRK(ACCR, IC, B0, B1) do { \
    unsigned key_ = (__float_as_uint(ACCR) & 0xFFFFFFC0u) | (IC); \
    unsigned nb1_; \
    asm("v_med3_u32 %0, %1, %2, %3" : "=v"(nb1_) : "v"(key_), "v"(B0), "v"(B1)); \
    B0 = key_ > (B0) ? key_ : (B0); \
    B1 = nb1_; \
} while (0)

// ---------------- pass 1: single-MFMA f16 scan + exact-f32 xn via C-init ----------------
// (R16-verified numerics: dot = ah·bh; xn exact via f32 C-init with +64 bias; med3 top-2
// trackers; pass2 exact-f32 refine absorbs the f16 error.)
// R17: per-super-tile hoisted LDS bases, FULL unroll of the t-loop (ds_read offsets become
// immediates; deep lgkmcnt pipelining), setprio raised once per super-tile.
// R18's fused 3-op asm TRK miscompiled (absmax 0.887) — reverted to this verified form.
__global__ __attribute__((amdgpu_flat_work_group_size(P1T, P1T)))
__attribute__((amdgpu_waves_per_eu(4)))
void k_pass1(const float* __restrict__ train,
             const unsigned* __restrict__ scale_u,
             const _Float16* __restrict__ Qhi,
             unsigned long long* __restrict__ cand) {
    __shared__ float s_inv[32];
    __shared__ __align__(16) float raw[2][RAWF];                     // 34560 B
    __shared__ __align__(16) unsigned char convb[2][NPT * TILE_B];   // 20480 B
    __shared__ __align__(16) float xnhb[2][NPT * 16];                // 1280 B (xn C-init per point)

    int tid = threadIdx.x;
    if (tid < 32) {
        float sc = __uint_as_float(scale_u[tid]);       // 0 for d>=27 (memset)
        s_inv[tid] = (sc != 0.f) ? 1.f / sc : 0.f;
    }
    int lane = tid & 63, w = tid >> 6;                  // w in [0,16)
    int l15 = lane & 15, quad = lane >> 4;
    int rdoff = quad * 256 + ((l15 ^ (quad << 2)) * 16);   // swizzled A-frag read offset (hoisted)

    h8 bhi[2];
#pragma unroll
    for (int j = 0; j < 2; ++j) {
        int qt = w * 2 + j;                             // query tile 0..31
        size_t e = (size_t)(qt * 16 + l15) * 32 + quad * 8;
        bhi[j] = *(const h8*)(Qhi + e);
    }

    // top-2 keys per (query-tile j, acc row r); 0 = -inf sentinel (real keys ~0x41BC.. +)
    unsigned kb0[2][4], kb1[2][4];
#pragma unroll
    for (int j = 0; j < 2; ++j)
#pragma unroll
        for (int r = 0; r < 4; ++r) { kb0[j][r] = 0u; kb1[j][r] = 0u; }

    int p0 = blockIdx.x * PTS_BLK;
    const float* gsup = train + (size_t)p0 * DIMS;   // 16B aligned (800*108 % 16 == 0)

    // async stage super-tile 0 (1024 threads: 4096 floats + 224 tail)
    {
        const float* gp = gsup; float* lp = raw[0];
        stage16(gp + tid * 4, lp + tid * 4);
        if (tid < 56) stage16(gp + 4096 + tid * 4, lp + 4096 + tid * 4);
    }

    for (int s = 0; s < NSUP; ++s) {
        __syncthreads();   // drains stage(s) vmcnt; raw[s&1] ready; convb[s&1] free (compute(s-2) done)

        if (s + 1 < NSUP) {   // async stage next super-tile; drains at next barrier
            const float* gp = gsup + (size_t)(s + 1) * RAWF;
            float* lp = raw[(s + 1) & 1];
            stage16(gp + tid * 4, lp + tid * 4);
            if (tid < 56) stage16(gp + 4096 + tid * 4, lp + 4096 + tid * 4);
        }

        // ---- conv(s): task = (point p, kblock gq of 8 dims); 640 tasks, waves 10..15 skip ----
        const float* rw = raw[s & 1];
        if (tid < PTS_SUP * 4) {
            int p = tid >> 2, gq = tid & 3;
            float x[8]; float part = 0.f;
#pragma unroll
            for (int i = 0; i < 8; ++i) {
                int d = gq * 8 + i;
                int dc = d < DIMS ? d : (DIMS - 1);     // clamp; s_inv[d>=27]=0 zeroes value
                float v = rw[p * DIMS + dc] * s_inv[d];
                x[i] = v;
                part = fmaf(v, v, part);
            }
            part += __shfl_xor(part, 1, 64);
            part += __shfl_xor(part, 2, 64);            // all 4 kblock-lanes hold xn
            h8 hv;
#pragma unroll
            for (int i = 0; i < 8; ++i) hv[i] = (_Float16)x[i];
            if (gq == 3)                                // one lane per point: exact f32 xn + bias
                xnhb[s & 1][p] = fmaf(-0.5f, part, 64.f);
            // XOR-swizzled write slot: (p&15)^(gq<<2)
            unsigned char* dstb = convb[s & 1] + (p >> 4) * TILE_B + gq * 256
                                  + (((p & 15) ^ (gq << 2)) * 16);
            *(h8*)dstb = hv;
        }

        // ---- compute(s-1): hoisted bases + full unroll; 1 MFMA + med3 top-2 per (j,tile) ----
        if (s > 0) {
            int ss = s - 1;
            const unsigned char* cb = convb[ss & 1] + rdoff;    // single base per super-tile
            const float* xb = xnhb[ss & 1] + quad * 4;
            unsigned icb = 63u - (unsigned)(ss * NPT);          // ic = icb - t (SGPR)
            __builtin_amdgcn_s_setprio(1);
#pragma unroll
            for (int t = 0; t < NPT; ++t) {
                h8 ahi = *(const h8*)(cb + t * TILE_B);         // offset-immediate ds_read
                f4v xnh4 = *(const f4v*)(xb + t * 16);
                unsigned ic = icb - (unsigned)t;
#pragma unroll
                for (int j = 0; j < 2; ++j) {
                    f4v acc = __builtin_amdgcn_mfma_f32_16x16x32_f16(ahi, bhi[j], xnh4, 0, 0, 0);
#pragma unroll
                    for (int r = 0; r < 4; ++r) TRK(acc[r], ic, kb0[j][r], kb1[j][r]);
                }
            }
            __builtin_amdgcn_s_setprio(0);
        }
    }

    // epilogue: compute last super-tile
    __syncthreads();
    {
        int ss = NSUP - 1;
        const unsigned char* cb = convb[ss & 1] + rdoff;
        const float* xb = xnhb[ss & 1] + quad * 4;
        unsigned icb = 63u - (unsigned)(ss * NPT);
        __builtin_amdgcn_s_setprio(1);
#pragma unroll
        for (int t = 0; t < NPT; ++t) {
            h8 ahi = *(const h8*)(cb + t * TILE_B);
            f4v xnh4 = *(const f4v*)(xb + t * 16);
            unsigned ic = icb - (unsigned)t;
#pragma unroll
            for (int j = 0; j < 2; ++j) {
                f4v acc = __builtin_amdgcn_mfma_f32_16x16x32_f16(ahi, bhi[j], xnh4, 0, 0, 0);
#pragma unroll
                for (int r = 0; r < 4; ++r) TRK(acc[r], ic, kb0[j][r], kb1[j][r]);
            }
        }
        __builtin_amdgcn_s_setprio(0);
    }

    // decode + cross-quad merge (4 disjoint point subsets per query) -> block top-3
    // sort64 = (~(key|63) << 32) | gidx : ascending u64 == exact lex (quantized d, idx)
    int g = blockIdx.x;
    int qr4 = quad * 4;
#pragma unroll
    for (int j = 0; j < 2; ++j) {
        unsigned long long t0 = U64MAX, t1 = U64MAX, t2 = U64MAX;
#pragma unroll
        for (int r = 0; r < 4; ++r) {
#pragma unroll
            for (int h = 0; h < 2; ++h) {
                unsigned k = h ? kb1[j][r] : kb0[j][r];
                unsigned tile = 63u - (k & 63u);
                unsigned gi = (unsigned)(p0 + (int)tile * 16 + qr4 + r);
                unsigned long long e = ((unsigned long long)(~(k | 63u)) << 32) | gi;
                ins3u64(e, t0, t1, t2);
            }
        }
#pragma unroll
        for (int step = 16; step <= 32; step <<= 1) {
            unsigned long long o0 = shfl_xor_u64(t0, step);
            unsigned long long o1 = shfl_xor_u64(t1, step);
            unsigned long long o2 = shfl_xor_u64(t2, step);
            ins3u64(o0, t0, t1, t2);
            ins3u64(o1, t0, t1, t2);
            ins3u64(o2, t0, t1, t2);
        }
        if (quad == 0) {
            int qq = (w * 2 + j) * 16 + l15;
            size_t off = (size_t)qq * NC + (size_t)g * KNN;
            cand[off + 0] = t0; cand[off + 1] = t1; cand[off + 2] = t2;
        }
    }
}

// branchless compare-exchange (ascending)
#define CE(a, b) do { unsigned long long lo_ = (a) < (b) ? (a) : (b); \
                      unsigned long long hi_ = (a) < (b) ? (b) : (a); \
                      (a) = lo_; (b) = hi_; } while (0)

// ---------------- pass 2: parallel u64 top-8 merge -> exact f32 refine -> vote ----------------
__global__ __launch_bounds__(P2T) void k_pass2(const unsigned long long* __restrict__ cand,
                                               const float* __restrict__ train,
                                               const float* __restrict__ query,
                                               const unsigned* __restrict__ scale_u,
                                               const float* __restrict__ labels,
                                               float* __restrict__ out) {
    __shared__ unsigned long long smerge[64];   // 8 waves x top-8
    int q = blockIdx.x;
    int tid = threadIdx.x, lane = tid & 63, w = tid >> 6;
    const unsigned long long* cd = cand + (size_t)q * NC;

    // phase A: each thread owns <=3 candidates (1500 / 512); sort-3 (named regs, rule #20)
    unsigned long long c0 = cd[tid];
    unsigned long long c1 = cd[tid + P2T];
    unsigned long long c2 = (tid + 2 * P2T < NC) ? cd[tid + 2 * P2T] : U64MAX;
    CE(c0, c1); CE(c0, c2); CE(c1, c2);   // ascending

    // phase B: per-wave top-8 by repeated butterfly-u64-min extraction; lane 0 -> LDS
#pragma unroll
    for (int k = 0; k < 8; ++k) {
        unsigned long long m = c0;
#pragma unroll
        for (int st = 1; st < 64; st <<= 1) {
            unsigned long long o = shfl_xor_u64(m, st);
            if (o < m) m = o;
        }
        if (lane == 0) smerge[w * 8 + k] = m;
        bool win = (c0 == m);                 // exactly one lane (unique idx, m < U64MAX)
        c0 = win ? c1 : c0;
        c1 = win ? c2 : c1;
        c2 = win ? U64MAX : c2;
    }
    __syncthreads();
    if (w != 0) return;

    // phase C (wave 0): merge 8x8 wave winners -> global top-8; lane k keeps idx of rank k
    int myi = 0x7fffffff;
    {
        unsigned long long cur = smerge[lane];   // 64 real, unique entries
#pragma unroll
        for (int k = 0; k < 8; ++k) {
            unsigned long long m = cur;
#pragma unroll
            for (int st = 1; st < 64; st <<= 1) {
                unsigned long long o = shfl_xor_u64(m, st);
                if (o < m) m = o;
            }
            if (lane == k) myi = (int)(unsigned)m;
            if (cur == m) cur = U64MAX;
        }
    }

    // exact f32 scaled query + qn (same op order as the verified path)
    float inv[DIMS], qs_[DIMS], qn_ = 0.f;
#pragma unroll
    for (int d = 0; d < DIMS; ++d) {
        float sc = __uint_as_float(scale_u[d]);
        float iv = (sc != 0.f) ? 1.f / sc : 0.f;
        float v = query[(size_t)q * DIMS + d] * iv;
        inv[d] = iv; qs_[d] = v;
        qn_ = fmaf(v, v, qn_);
    }

    float myd2 = 3.4e38f;
    if (lane < 8) {
        const float* r = train + (size_t)myi * DIMS;
        float xnv = 0.f, dot = 0.f;
#pragma unroll
        for (int d = 0; d < DIMS; ++d) {
            float v = r[d] * inv[d];
            xnv = fmaf(v, v, xnv);
            dot = fmaf(qs_[d], v, dot);
        }
        myd2 = fmaf(-2.f, dot, qn_ + xnv);
    }

    float bd[KNN] = {3.4e38f, 3.4e38f, 3.4e38f};
    int   bi[KNN] = {0x7fffffff, 0x7fffffff, 0x7fffffff};
#pragma unroll
    for (int k = 0; k < 8; ++k) {
        float dk = __shfl(myd2, k, 64);
        int   ik = __shfl(myi, k, 64);
        insert3(dk, ik, bd, bi);
    }

    if (lane == 0) {
        float kd[KNN];
#pragma unroll
        for (int k = 0; k < KNN; ++k) kd[k] = sqrtf(fmaxf(bd[k], 0.f));
        float lab[KNN][NCLS];
#pragma unroll
        for (int k = 0; k < KNN; ++k) {
            const float* lr = labels + (size_t)bi[k] * NCLS;
#pragma unroll
            for (int c = 0; c < NCLS; ++c) lab[k][c] = lr[c];
        }
        float votes[NCLS];
#pragma unroll
        for (int c = 0; c < NCLS; ++c) votes[c] = 0.f;
#pragma unroll
        for (int k = 0; k < KNN; ++k) {
            float ks = (kd[k] == 0.f) ? 1.f : kd[k];
#pragma unroll
            for (int c = 0; c < NCLS; ++c) votes[c] += lab[k][c] / ks;
        }
        int best = 0; float bv = votes[0];
#pragma unroll
        for (int c = 1; c < NCLS; ++c) { if (votes[c] > bv) { bv = votes[c]; best = c; } }
        bool zero_hit = (kd[0] == 0.f);
#pragma unroll
        for (int k = 0; k < KNN; ++k) out[(size_t)q * KNN + k] = kd[k];
        float* ro = out + (size_t)BQ * KNN + (size_t)q * NCLS;
#pragma unroll
        for (int c = 0; c < NCLS; ++c)
            ro[c] = zero_hit ? lab[0][c] : ((c == best) ? 1.f : 0.f);
    }
}

extern "C" void kernel_launch(void* const* d_in, const int* in_sizes, int n_in,
                              void* d_out, int out_size, void* d_ws, size_t ws_size,
                              hipStream_t stream) {
    const float* query  = (const float*)d_in[0];
    const float* train  = (const float*)d_in[1];
    const float* labels = (const float*)d_in[2];
    float* out = (float*)d_out;

    // ws layout:
    //   [0)       scale_u: 32 u32 (128 B)
    //   [128)     Qhi: 512*32 f16 (32768 B)
    //   [32896)   cand: 512*1500 u64 (6144000 B)   total ~6.2 MB
    char* ws = (char*)d_ws;
    unsigned*  scale_u = (unsigned*)ws;
    _Float16*  Qhi = (_Float16*)(ws + 128);
    unsigned long long* cand = (unsigned long long*)(ws + 32896);

    hipMemsetAsync(ws, 0, 128, stream);  // zero scale accumulators
    k_scale<<<SCB, 256, 0, stream>>>(train, scale_u);
    k_qprep<<<8, 64, 0, stream>>>(query, scale_u, Qhi);
    k_pass1<<<NB, P1T, 0, stream>>>(train, scale_u, Qhi, cand);
    k_pass2<<<BQ, P2T, 0, stream>>>(cand, train, query, scale_u, labels, out);
}